// Round 1
// baseline (96.381 us; speedup 1.0000x reference)
//
#include <hip/hip_runtime.h>
#include <math.h>

#define NN   65536
#define DEGC 16
#define DD   64
#define DD2  128
#define BB   1024
#define NEGC 10
#define NROWS (BB + BB + NEGC)   // 2058

// ---------------------------------------------------------------------------
// Phase 0b: mark hop-1 nodes actually needed (neighbors of queried nodes).
// ---------------------------------------------------------------------------
__global__ void mark_flags_kernel(const int* __restrict__ adj,
                                  const int* __restrict__ in1,
                                  const int* __restrict__ in2,
                                  const int* __restrict__ neg,
                                  unsigned char* __restrict__ flags) {
    int r = blockIdx.x * blockDim.x + threadIdx.x;
    if (r >= NROWS) return;
    int node = (r < BB) ? in1[r] : (r < 2 * BB ? in2[r - BB] : neg[r - 2 * BB]);
    const int* arow = adj + (long)node * DEGC;
    #pragma unroll
    for (int k = 0; k < DEGC; ++k) flags[arow[k]] = 1;
}

// ---------------------------------------------------------------------------
// Phase 1: h1[n] = tanh(concat(feat[n], sum_k feat[adj[n][k]]) @ W1^T + b1)
// One wave per node. W1 transposed in LDS: wt[i*64+j] = W1[j][i].
// ---------------------------------------------------------------------------
__global__ __launch_bounds__(256) void hop1_kernel(
    const float* __restrict__ feat, const int* __restrict__ adj,
    const float* __restrict__ W1, const float* __restrict__ b1,
    const unsigned char* __restrict__ flags, float* __restrict__ h1) {

    __shared__ float wt[DD2 * DD];        // 32 KB
    __shared__ float cbuf[4][DD2];        // 2 KB, per-wave private row

    int tid = threadIdx.x;
    // Load W1 transposed (one-time; write conflicts don't matter here).
    #pragma unroll
    for (int t = 0; t < (DD2 * DD) / 256; ++t) {
        int lin = t * 256 + tid;
        int i = lin & (DD2 - 1);
        int j = lin >> 7;
        wt[i * DD + j] = W1[j * DD2 + i];
    }
    __syncthreads();

    int wave = tid >> 6, lane = tid & 63;
    int gw = blockIdx.x * 4 + wave;
    int stride = gridDim.x * 4;           // grid chosen so NN % stride == 0
    float bias = b1[lane];

    for (int n = gw; n < NN; n += stride) {
        bool active = (flags[n] != 0);    // wave-uniform
        if (active) {
            const int* arow = adj + (long)n * DEGC;   // wave-uniform -> s_load
            float s = 0.f;
            #pragma unroll
            for (int k = 0; k < DEGC; ++k) {
                int nbr = arow[k];
                s += feat[(long)nbr * DD + lane];     // coalesced 256B row
            }
            cbuf[wave][lane]      = feat[(long)n * DD + lane];
            cbuf[wave][DD + lane] = s;
        }
        __syncthreads();
        if (active) {
            float acc = bias;
            #pragma unroll
            for (int i4 = 0; i4 < DD2 / 4; ++i4) {
                float4 cv = *(const float4*)&cbuf[wave][i4 * 4];
                acc += cv.x * wt[(i4 * 4 + 0) * DD + lane];
                acc += cv.y * wt[(i4 * 4 + 1) * DD + lane];
                acc += cv.z * wt[(i4 * 4 + 2) * DD + lane];
                acc += cv.w * wt[(i4 * 4 + 3) * DD + lane];
            }
            h1[(long)n * DD + lane] = tanhf(acc);
        }
        __syncthreads();
    }
}

// ---------------------------------------------------------------------------
// Phase 2: per queried row r: out = normalize(concat(feat[m], sum_k h1[adj[m][k]]) @ W2^T + b2)
// One wave per row; W2 transposed in LDS (64 KB). Lane j owns outputs j and j+64.
// ---------------------------------------------------------------------------
__global__ __launch_bounds__(256) void hop2_kernel(
    const float* __restrict__ feat, const int* __restrict__ adj,
    const float* __restrict__ h1,
    const int* __restrict__ in1, const int* __restrict__ in2,
    const int* __restrict__ neg,
    const float* __restrict__ W2, const float* __restrict__ b2,
    float* __restrict__ out) {

    __shared__ float wt2[DD2 * DD2];      // 64 KB: wt2[i*128+j] = W2[j][i]
    __shared__ float cbuf[4][DD2];        // 2 KB

    int tid = threadIdx.x;
    #pragma unroll
    for (int t = 0; t < (DD2 * DD2) / 256; ++t) {
        int lin = t * 256 + tid;
        int i = lin & (DD2 - 1);
        int j = lin >> 7;
        wt2[i * DD2 + j] = W2[j * DD2 + i];
    }
    __syncthreads();

    int wave = tid >> 6, lane = tid & 63;
    int r = blockIdx.x * 4 + wave;
    bool active = (r < NROWS);
    if (active) {
        int node = (r < BB) ? in1[r] : (r < 2 * BB ? in2[r - BB] : neg[r - 2 * BB]);
        const int* arow = adj + (long)node * DEGC;
        float s = 0.f;
        #pragma unroll
        for (int k = 0; k < DEGC; ++k) {
            int nbr = arow[k];
            s += h1[(long)nbr * DD + lane];
        }
        cbuf[wave][lane]      = feat[(long)node * DD + lane];
        cbuf[wave][DD + lane] = s;
    }
    __syncthreads();
    if (active) {
        float accA = b2[lane];
        float accB = b2[DD + lane];
        #pragma unroll
        for (int i4 = 0; i4 < DD2 / 4; ++i4) {
            float4 cv = *(const float4*)&cbuf[wave][i4 * 4];
            #pragma unroll
            for (int t = 0; t < 4; ++t) {
                int i = i4 * 4 + t;
                float cvt = (&cv.x)[t];
                accA += cvt * wt2[i * DD2 + lane];
                accB += cvt * wt2[i * DD2 + DD + lane];
            }
        }
        float ss = accA * accA + accB * accB;
        #pragma unroll
        for (int off = 32; off > 0; off >>= 1) ss += __shfl_xor(ss, off, 64);
        float nrm = fmaxf(sqrtf(ss), 1e-12f);
        float inv = 1.0f / nrm;
        out[(long)r * DD2 + lane]      = accA * inv;
        out[(long)r * DD2 + DD + lane] = accB * inv;
    }
}

// ---------------------------------------------------------------------------
extern "C" void kernel_launch(void* const* d_in, const int* in_sizes, int n_in,
                              void* d_out, int out_size, void* d_ws, size_t ws_size,
                              hipStream_t stream) {
    const float* feat = (const float*)d_in[0];
    const int*   adj  = (const int*)d_in[1];
    const int*   in1  = (const int*)d_in[2];
    const int*   in2  = (const int*)d_in[3];
    const int*   neg  = (const int*)d_in[4];
    const float* W1   = (const float*)d_in[5];
    const float* b1   = (const float*)d_in[6];
    const float* W2   = (const float*)d_in[7];
    const float* b2   = (const float*)d_in[8];
    float* out = (float*)d_out;

    float* h1 = (float*)d_ws;                                   // 16 MB
    unsigned char* flags = (unsigned char*)d_ws + (size_t)NN * DD * 4;  // 64 KB

    hipMemsetAsync(flags, 0, NN, stream);
    mark_flags_kernel<<<(NROWS + 255) / 256, 256, 0, stream>>>(adj, in1, in2, neg, flags);
    // 1024 blocks * 4 waves = 4096 waves; 65536 % 4096 == 0 (uniform trip count)
    hop1_kernel<<<1024, 256, 0, stream>>>(feat, adj, W1, b1, flags, h1);
    hop2_kernel<<<(NROWS + 3) / 4, 256, 0, stream>>>(feat, adj, h1, in1, in2, neg, W2, b2, out);
}